// Round 16
// baseline (30.996 us; speedup 1.0000x reference)
//
#include <hip/hip_runtime.h>
#include <hip/hip_fp16.h>
#include <math.h>

#define TPB 256
#define NODES 16
#define BLOCKS 2048

typedef float f32x4 __attribute__((ext_vector_type(4)));
typedef _Float16 half4 __attribute__((ext_vector_type(4)));
typedef _Float16 h2 __attribute__((ext_vector_type(2)));

#define LOG2E 1.44269504088896340736f
#define LN2   0.69314718055994530942f

__device__ __forceinline__ _Float16 hx2(_Float16 x) {
    __half h = __builtin_bit_cast(__half, x);
    __half r = hexp2(h);
    return __builtin_bit_cast(_Float16, r);
}

// packed f16 softplus in log2 domain (see R15). 2 values per call.
__device__ __forceinline__ unsigned int sp2_pos(float v0, float v1) {
    h2 h = __builtin_bit_cast(h2, __builtin_amdgcn_cvt_pkrtz(v0, v1));
    h2 e = { hx2((_Float16)(-h[0])), hx2((_Float16)(-h[1])) };
    const h2 c3 = {(_Float16)0.154358f,  (_Float16)0.154358f};
    const h2 c2 = {(_Float16)-0.571177f, (_Float16)-0.571177f};
    const h2 c1 = {(_Float16)1.416467f,  (_Float16)1.416467f};
    const h2 c0 = {(_Float16)0.000837f,  (_Float16)0.000837f};
    h2 p = __builtin_elementwise_fma(e,
             __builtin_elementwise_fma(e,
               __builtin_elementwise_fma(e, c3, c2), c1), c0);
    h2 r = h + p;
    return __builtin_bit_cast(unsigned int, r);
}
__device__ __forceinline__ unsigned int sp2_any(float v0, float v1) {
    h2 h = __builtin_bit_cast(h2, __builtin_amdgcn_cvt_pkrtz(v0, v1));
    const h2 z = {(_Float16)0.0f, (_Float16)0.0f};
    h2 m  = __builtin_elementwise_max(h, z);
    h2 nt = __builtin_elementwise_min(h, z - h);   // -|t|
    h2 e = { hx2(nt[0]), hx2(nt[1]) };
    const h2 c3 = {(_Float16)0.154358f,  (_Float16)0.154358f};
    const h2 c2 = {(_Float16)-0.571177f, (_Float16)-0.571177f};
    const h2 c1 = {(_Float16)1.416467f,  (_Float16)1.416467f};
    const h2 c0 = {(_Float16)0.000837f,  (_Float16)0.000837f};
    h2 p = __builtin_elementwise_fma(e,
             __builtin_elementwise_fma(e,
               __builtin_elementwise_fma(e, c3, c2), c1), c0);
    h2 r = m + p;
    return __builtin_bit_cast(unsigned int, r);
}
__device__ __forceinline__ unsigned int pk2(float a, float b) {
    return __builtin_bit_cast(unsigned int, __builtin_amdgcn_cvt_pkrtz(a, b));
}
__device__ __forceinline__ half4 h4(uint2 u) {
    return __builtin_bit_cast(half4, u);
}

__global__ __launch_bounds__(TPB, 4) void mlp_mfma_kernel(
    const float* __restrict__ Fs,
    const float* __restrict__ W1, const float* __restrict__ b1,
    const float* __restrict__ W2, const float* __restrict__ b2,
    const float* __restrict__ W3, const float* __restrict__ b3,
    const float* __restrict__ W4, const float* __restrict__ b4,
    float* __restrict__ out, int n, int iters)
{
    // per-wave: 2 groups x 64 samples x 5 uint2 -> 20 KiB/block (8 blocks/CU)
    __shared__ uint2 lds[4][2][320];
    const int tid = threadIdx.x;
    const int l = tid & 63, w = tid >> 6;
    const int g = l >> 4, c = l & 15;

    // ---- one-time fragments/biases; no weight loads in the loop ----
    half4 a1lo, a1hi, a2, a3, a4;
    f32x4 cb1, cb2, cb3, cb4;
    #pragma unroll
    for (int j = 0; j < 4; ++j) {
        a1lo[j] = (_Float16)(W1[(4*g+j)*NODES + c] * LOG2E);
        a1hi[j] = (_Float16)((g == 0 && j < 3) ? W1[(16+j)*NODES + c] * LOG2E : 0.0f);
        a2[j]   = (_Float16)W2[(4*g+j)*NODES + c];
        a3[j]   = (_Float16)W3[(4*g+j)*NODES + c];
        a4[j]   = (_Float16)(W4[4*g+j] * LN2);
    }
    const float b4s = b4[0];
    #pragma unroll
    for (int i = 0; i < 4; ++i) {
        cb1[i] = b1[4*g+i] * LOG2E;
        cb2[i] = b2[4*g+i] * LOG2E;
        cb3[i] = b3[4*g+i] * LOG2E;
        cb4[i] = b4s;
    }

    uint2* basepA = &lds[w][0][0];
    uint2* basepB = &lds[w][1][0];
    const long long s0 = ((long long)blockIdx.x * 4 + w) * (128LL * iters);
    if (s0 >= n) return;

    float frA[9], frB[9];

    #define LOADF(R, S)                                                          \
        do {                                                                     \
            long long sE = (S) + l; if (sE > n - 1) sE = n - 1;                  \
            const float* fp = Fs + sE * 9;                                       \
            _Pragma("unroll")                                                    \
            for (int q = 0; q < 9; ++q) (R)[q] = fp[q];                          \
        } while (0)

    #define FEATW(R, B)                                                          \
        do {                                                                     \
            float a = (R)[0], b = (R)[1], cc = (R)[2];                           \
            float d = (R)[3], e = (R)[4], f5 = (R)[5];                           \
            float g7 = (R)[6], h7 = (R)[7], i8 = (R)[8];                         \
            float C00 = e * i8 - f5 * h7;                                        \
            float C01 = f5 * g7 - d * i8;                                        \
            float C02 = d * h7 - e * g7;                                         \
            float det = fmaf(a, C00, fmaf(b, C01, cc * C02));                    \
            float C10 = cc * h7 - b * i8;                                        \
            float C11 = a * i8 - cc * g7;                                        \
            float C12 = b * g7 - a * h7;                                         \
            float C20 = b * f5 - cc * e;                                         \
            float C21 = cc * d - a * f5;                                         \
            float C22 = a * e - b * d;                                           \
            uint2 v;                                                             \
            v.x = pk2(a,   b);   v.y = pk2(cc,  d);    (B)[l*5 + 0] = v;         \
            v.x = pk2(e,   f5);  v.y = pk2(g7,  h7);   (B)[l*5 + 1] = v;         \
            v.x = pk2(i8,  C00); v.y = pk2(C01, C02);  (B)[l*5 + 2] = v;         \
            v.x = pk2(C10, C11); v.y = pk2(C12, C20);  (B)[l*5 + 3] = v;         \
            v.x = pk2(C21, C22); v.y = pk2(det, 0.0f); (B)[l*5 + 4] = v;         \
        } while (0)

    LOADF(frA, s0);
    LOADF(frB, s0 + 64);

    for (int it = 0; it < iters; ++it) {
        long long ws = s0 + (long long)it * 128;
        if (ws >= n) break;

        FEATW(frA, basepA);
        FEATW(frB, basepB);
        asm volatile("s_waitcnt lgkmcnt(0)" ::: "memory");

        // prefetch next iteration's F (both groups) under this iter's compute
        const bool havenext = (it + 1 < iters) && (ws + 128 < n);
        if (havenext) {
            LOADF(frA, ws + 128);
            LOADF(frB, ws + 192);
        }

        // ---- gathers (A then B; independent) ----
        uint2 Alo0 = basepA[(16*0 + c)*5 + g];
        uint2 Alo1 = basepA[(16*1 + c)*5 + g];
        uint2 Alo2 = basepA[(16*2 + c)*5 + g];
        uint2 Alo3 = basepA[(16*3 + c)*5 + g];
        uint2 Ahi0 = basepA[(16*0 + c)*5 + 4];
        uint2 Ahi1 = basepA[(16*1 + c)*5 + 4];
        uint2 Ahi2 = basepA[(16*2 + c)*5 + 4];
        uint2 Ahi3 = basepA[(16*3 + c)*5 + 4];
        uint2 Blo0 = basepB[(16*0 + c)*5 + g];
        uint2 Blo1 = basepB[(16*1 + c)*5 + g];
        uint2 Blo2 = basepB[(16*2 + c)*5 + g];
        uint2 Blo3 = basepB[(16*3 + c)*5 + g];
        uint2 Bhi0 = basepB[(16*0 + c)*5 + 4];
        uint2 Bhi1 = basepB[(16*1 + c)*5 + 4];
        uint2 Bhi2 = basepB[(16*2 + c)*5 + 4];
        uint2 Bhi3 = basepB[(16*3 + c)*5 + 4];

        // ---- Layer 1 (A and B interleaved: 16 independent MFMAs) ----
        f32x4 tA0 = __builtin_amdgcn_mfma_f32_16x16x16f16(a1lo, h4(Alo0), cb1, 0, 0, 0);
        f32x4 tB0 = __builtin_amdgcn_mfma_f32_16x16x16f16(a1lo, h4(Blo0), cb1, 0, 0, 0);
        f32x4 tA1 = __builtin_amdgcn_mfma_f32_16x16x16f16(a1lo, h4(Alo1), cb1, 0, 0, 0);
        f32x4 tB1 = __builtin_amdgcn_mfma_f32_16x16x16f16(a1lo, h4(Blo1), cb1, 0, 0, 0);
        f32x4 tA2 = __builtin_amdgcn_mfma_f32_16x16x16f16(a1lo, h4(Alo2), cb1, 0, 0, 0);
        f32x4 tB2 = __builtin_amdgcn_mfma_f32_16x16x16f16(a1lo, h4(Blo2), cb1, 0, 0, 0);
        f32x4 tA3 = __builtin_amdgcn_mfma_f32_16x16x16f16(a1lo, h4(Alo3), cb1, 0, 0, 0);
        f32x4 tB3 = __builtin_amdgcn_mfma_f32_16x16x16f16(a1lo, h4(Blo3), cb1, 0, 0, 0);
        tA0 = __builtin_amdgcn_mfma_f32_16x16x16f16(a1hi, h4(Ahi0), tA0, 0, 0, 0);
        tB0 = __builtin_amdgcn_mfma_f32_16x16x16f16(a1hi, h4(Bhi0), tB0, 0, 0, 0);
        tA1 = __builtin_amdgcn_mfma_f32_16x16x16f16(a1hi, h4(Ahi1), tA1, 0, 0, 0);
        tB1 = __builtin_amdgcn_mfma_f32_16x16x16f16(a1hi, h4(Bhi1), tB1, 0, 0, 0);
        tA2 = __builtin_amdgcn_mfma_f32_16x16x16f16(a1hi, h4(Ahi2), tA2, 0, 0, 0);
        tB2 = __builtin_amdgcn_mfma_f32_16x16x16f16(a1hi, h4(Bhi2), tB2, 0, 0, 0);
        tA3 = __builtin_amdgcn_mfma_f32_16x16x16f16(a1hi, h4(Ahi3), tA3, 0, 0, 0);
        tB3 = __builtin_amdgcn_mfma_f32_16x16x16f16(a1hi, h4(Bhi3), tB3, 0, 0, 0);

        uint2 uA0, uA1, uA2, uA3, uB0, uB1, uB2, uB3;
        uA0.x = sp2_any(tA0[0], tA0[1]); uA0.y = sp2_any(tA0[2], tA0[3]);
        uB0.x = sp2_any(tB0[0], tB0[1]); uB0.y = sp2_any(tB0[2], tB0[3]);
        uA1.x = sp2_any(tA1[0], tA1[1]); uA1.y = sp2_any(tA1[2], tA1[3]);
        uB1.x = sp2_any(tB1[0], tB1[1]); uB1.y = sp2_any(tB1[2], tB1[3]);
        uA2.x = sp2_any(tA2[0], tA2[1]); uA2.y = sp2_any(tA2[2], tA2[3]);
        uB2.x = sp2_any(tB2[0], tB2[1]); uB2.y = sp2_any(tB2[2], tB2[3]);
        uA3.x = sp2_any(tA3[0], tA3[1]); uA3.y = sp2_any(tA3[2], tA3[3]);
        uB3.x = sp2_any(tB3[0], tB3[1]); uB3.y = sp2_any(tB3[2], tB3[3]);

        // ---- Layer 2 ----
        f32x4 dA0 = __builtin_amdgcn_mfma_f32_16x16x16f16(a2, h4(uA0), cb2, 0, 0, 0);
        f32x4 dB0 = __builtin_amdgcn_mfma_f32_16x16x16f16(a2, h4(uB0), cb2, 0, 0, 0);
        f32x4 dA1 = __builtin_amdgcn_mfma_f32_16x16x16f16(a2, h4(uA1), cb2, 0, 0, 0);
        f32x4 dB1 = __builtin_amdgcn_mfma_f32_16x16x16f16(a2, h4(uB1), cb2, 0, 0, 0);
        f32x4 dA2 = __builtin_amdgcn_mfma_f32_16x16x16f16(a2, h4(uA2), cb2, 0, 0, 0);
        f32x4 dB2 = __builtin_amdgcn_mfma_f32_16x16x16f16(a2, h4(uB2), cb2, 0, 0, 0);
        f32x4 dA3 = __builtin_amdgcn_mfma_f32_16x16x16f16(a2, h4(uA3), cb2, 0, 0, 0);
        f32x4 dB3 = __builtin_amdgcn_mfma_f32_16x16x16f16(a2, h4(uB3), cb2, 0, 0, 0);

        uA0.x = sp2_pos(dA0[0], dA0[1]); uA0.y = sp2_pos(dA0[2], dA0[3]);
        uB0.x = sp2_pos(dB0[0], dB0[1]); uB0.y = sp2_pos(dB0[2], dB0[3]);
        uA1.x = sp2_pos(dA1[0], dA1[1]); uA1.y = sp2_pos(dA1[2], dA1[3]);
        uB1.x = sp2_pos(dB1[0], dB1[1]); uB1.y = sp2_pos(dB1[2], dB1[3]);
        uA2.x = sp2_pos(dA2[0], dA2[1]); uA2.y = sp2_pos(dA2[2], dA2[3]);
        uB2.x = sp2_pos(dB2[0], dB2[1]); uB2.y = sp2_pos(dB2[2], dB2[3]);
        uA3.x = sp2_pos(dA3[0], dA3[1]); uA3.y = sp2_pos(dA3[2], dA3[3]);
        uB3.x = sp2_pos(dB3[0], dB3[1]); uB3.y = sp2_pos(dB3[2], dB3[3]);

        // ---- Layer 3 ----
        dA0 = __builtin_amdgcn_mfma_f32_16x16x16f16(a3, h4(uA0), cb3, 0, 0, 0);
        dB0 = __builtin_amdgcn_mfma_f32_16x16x16f16(a3, h4(uB0), cb3, 0, 0, 0);
        dA1 = __builtin_amdgcn_mfma_f32_16x16x16f16(a3, h4(uA1), cb3, 0, 0, 0);
        dB1 = __builtin_amdgcn_mfma_f32_16x16x16f16(a3, h4(uB1), cb3, 0, 0, 0);
        dA2 = __builtin_amdgcn_mfma_f32_16x16x16f16(a3, h4(uA2), cb3, 0, 0, 0);
        dB2 = __builtin_amdgcn_mfma_f32_16x16x16f16(a3, h4(uB2), cb3, 0, 0, 0);
        dA3 = __builtin_amdgcn_mfma_f32_16x16x16f16(a3, h4(uA3), cb3, 0, 0, 0);
        dB3 = __builtin_amdgcn_mfma_f32_16x16x16f16(a3, h4(uB3), cb3, 0, 0, 0);

        uA0.x = sp2_pos(dA0[0], dA0[1]); uA0.y = sp2_pos(dA0[2], dA0[3]);
        uB0.x = sp2_pos(dB0[0], dB0[1]); uB0.y = sp2_pos(dB0[2], dB0[3]);
        uA1.x = sp2_pos(dA1[0], dA1[1]); uA1.y = sp2_pos(dA1[2], dA1[3]);
        uB1.x = sp2_pos(dB1[0], dB1[1]); uB1.y = sp2_pos(dB1[2], dB1[3]);
        uA2.x = sp2_pos(dA2[0], dA2[1]); uA2.y = sp2_pos(dA2[2], dA2[3]);
        uB2.x = sp2_pos(dB2[0], dB2[1]); uB2.y = sp2_pos(dB2[2], dB2[3]);
        uA3.x = sp2_pos(dA3[0], dA3[1]); uA3.y = sp2_pos(dA3[2], dA3[3]);
        uB3.x = sp2_pos(dB3[0], dB3[1]); uB3.y = sp2_pos(dB3[2], dB3[3]);

        // ---- Layer 4 (replicated-A): D[m][s] = y[s] ----
        f32x4 eA0 = __builtin_amdgcn_mfma_f32_16x16x16f16(a4, h4(uA0), cb4, 0, 0, 0);
        f32x4 eB0 = __builtin_amdgcn_mfma_f32_16x16x16f16(a4, h4(uB0), cb4, 0, 0, 0);
        f32x4 eA1 = __builtin_amdgcn_mfma_f32_16x16x16f16(a4, h4(uA1), cb4, 0, 0, 0);
        f32x4 eB1 = __builtin_amdgcn_mfma_f32_16x16x16f16(a4, h4(uB1), cb4, 0, 0, 0);
        f32x4 eA2 = __builtin_amdgcn_mfma_f32_16x16x16f16(a4, h4(uA2), cb4, 0, 0, 0);
        f32x4 eB2 = __builtin_amdgcn_mfma_f32_16x16x16f16(a4, h4(uB2), cb4, 0, 0, 0);
        f32x4 eA3 = __builtin_amdgcn_mfma_f32_16x16x16f16(a4, h4(uA3), cb4, 0, 0, 0);
        f32x4 eB3 = __builtin_amdgcn_mfma_f32_16x16x16f16(a4, h4(uB3), cb4, 0, 0, 0);

        float yA = (g == 0) ? eA0[0] : ((g == 1) ? eA1[0] : ((g == 2) ? eA2[0] : eA3[0]));
        float yB = (g == 0) ? eB0[0] : ((g == 1) ? eB1[0] : ((g == 2) ? eB2[0] : eB3[0]));
        if (ws + l < n)      out[ws + l] = yA;
        if (ws + 64 + l < n) out[ws + 64 + l] = yB;
    }
    #undef LOADF
    #undef FEATW
}

extern "C" void kernel_launch(void* const* d_in, const int* in_sizes, int n_in,
                              void* d_out, int out_size, void* d_ws, size_t ws_size,
                              hipStream_t stream) {
    const float* Fs = (const float*)d_in[0];
    const float* W1 = (const float*)d_in[1];
    const float* b1 = (const float*)d_in[2];
    const float* W2 = (const float*)d_in[3];
    const float* b2 = (const float*)d_in[4];
    const float* W3 = (const float*)d_in[5];
    const float* b3 = (const float*)d_in[6];
    const float* W4 = (const float*)d_in[7];
    const float* b4 = (const float*)d_in[8];
    float* out = (float*)d_out;

    int n = in_sizes[0] / 9;
    long long per_wave = 128;
    long long waves = (long long)BLOCKS * 4;
    int iters = (int)((n + waves * per_wave - 1) / (waves * per_wave));
    mlp_mfma_kernel<<<BLOCKS, TPB, 0, stream>>>(Fs, W1, b1, W2, b2, W3, b3, W4, b4,
                                                out, n, iters);
}

// Round 17
// 28.122 us; speedup vs baseline: 1.1022x; 1.1022x over previous
//
#include <hip/hip_runtime.h>
#include <hip/hip_fp16.h>
#include <math.h>

#define TPB 256
#define NODES 16
#define BLOCKS 2048

typedef float f32x4 __attribute__((ext_vector_type(4)));
typedef _Float16 half4 __attribute__((ext_vector_type(4)));
typedef _Float16 half8 __attribute__((ext_vector_type(8)));
typedef _Float16 h2 __attribute__((ext_vector_type(2)));

#define LOG2E 1.44269504088896340736f
#define LN2   0.69314718055994530942f

__device__ __forceinline__ _Float16 hx2(_Float16 x) {
    __half h = __builtin_bit_cast(__half, x);
    __half r = hexp2(h);
    return __builtin_bit_cast(_Float16, r);
}

// packed f16 softplus in log2 domain, 2 values per call, 3-FMA form.
// softplus(t*ln2)/ln2 = max(t,0) + log2(1+2^-|t|);  log2(1+e) ~= e*(c1+e*(c2+e*c3))
__device__ __forceinline__ unsigned int sp2_pos(float v0, float v1) {
    // t >= 0 guaranteed (W2,W3 >= 0 via jnp.abs, h >= 0, b = 0)
    h2 h = __builtin_bit_cast(h2, __builtin_amdgcn_cvt_pkrtz(v0, v1));
    h2 e = { hx2((_Float16)(-h[0])), hx2((_Float16)(-h[1])) };
    const h2 c3 = {(_Float16)0.154358f,  (_Float16)0.154358f};
    const h2 c2 = {(_Float16)-0.571177f, (_Float16)-0.571177f};
    const h2 c1 = {(_Float16)1.416467f,  (_Float16)1.416467f};
    h2 q = __builtin_elementwise_fma(e, __builtin_elementwise_fma(e, c3, c2), c1);
    h2 r = __builtin_elementwise_fma(e, q, h);
    return __builtin_bit_cast(unsigned int, r);
}
__device__ __forceinline__ unsigned int sp2_any(float v0, float v1) {
    h2 h = __builtin_bit_cast(h2, __builtin_amdgcn_cvt_pkrtz(v0, v1));
    const h2 z = {(_Float16)0.0f, (_Float16)0.0f};
    h2 m  = __builtin_elementwise_max(h, z);
    h2 nt = __builtin_elementwise_min(h, -h);   // -|t| (neg folds to modifier)
    h2 e = { hx2(nt[0]), hx2(nt[1]) };
    const h2 c3 = {(_Float16)0.154358f,  (_Float16)0.154358f};
    const h2 c2 = {(_Float16)-0.571177f, (_Float16)-0.571177f};
    const h2 c1 = {(_Float16)1.416467f,  (_Float16)1.416467f};
    h2 q = __builtin_elementwise_fma(e, __builtin_elementwise_fma(e, c3, c2), c1);
    h2 r = __builtin_elementwise_fma(e, q, m);
    return __builtin_bit_cast(unsigned int, r);
}
__device__ __forceinline__ unsigned int pk2(float a, float b) {
    return __builtin_bit_cast(unsigned int, __builtin_amdgcn_cvt_pkrtz(a, b));
}
__device__ __forceinline__ half4 h4(uint2 u) {
    return __builtin_bit_cast(half4, u);
}
__device__ __forceinline__ half8 h8(uint2 lo, uint2 hi) {
    uint4 u; u.x = lo.x; u.y = lo.y; u.z = hi.x; u.w = hi.y;
    return __builtin_bit_cast(half8, u);
}

__global__ __launch_bounds__(TPB, 4) void mlp_mfma_kernel(
    const float* __restrict__ Fs,
    const float* __restrict__ W1, const float* __restrict__ b1,
    const float* __restrict__ W2, const float* __restrict__ b2,
    const float* __restrict__ W3, const float* __restrict__ b3,
    const float* __restrict__ W4, const float* __restrict__ b4,
    float* __restrict__ out, int n, int iters)
{
    __shared__ uint2 lds[4][320];        // per-wave: 64 samples x 5 uint2 (19 f16 feats + pad)
    const int tid = threadIdx.x;
    const int l = tid & 63, w = tid >> 6;
    const int g = l >> 4, c = l & 15;

    // ---- one-time fragments/biases; no weight loads in the loop ----
    // L1: single K=32 MFMA. A8: j=0..3 -> k=4g+j; j=4..7 -> k=16+4g+(j-4)
    //     (W1 rows 19..31 are zero, so B hi garbage-but-finite is safe for g>0).
    // L4: replicated-A trick (all rows = W4*ln2), C = b4 -> D[m][s] = y[s].
    half8 a1;
    half4 a2, a3, a4;
    f32x4 cb1, cb2, cb3, cb4;
    #pragma unroll
    for (int j = 0; j < 4; ++j) {
        a1[j]   = (_Float16)(W1[(4*g+j)*NODES + c] * LOG2E);
        a1[4+j] = (_Float16)((g == 0 && j < 3) ? W1[(16+j)*NODES + c] * LOG2E : 0.0f);
        a2[j]   = (_Float16)W2[(4*g+j)*NODES + c];
        a3[j]   = (_Float16)W3[(4*g+j)*NODES + c];
        a4[j]   = (_Float16)(W4[4*g+j] * LN2);
    }
    const float b4s = b4[0];
    #pragma unroll
    for (int i = 0; i < 4; ++i) {
        cb1[i] = b1[4*g+i] * LOG2E;
        cb2[i] = b2[4*g+i] * LOG2E;
        cb3[i] = b3[4*g+i] * LOG2E;
        cb4[i] = b4s;
    }

    uint2* basep = &lds[w][0];
    const long long s0 = ((long long)blockIdx.x * 4 + w) * (64LL * iters);
    if (s0 >= n) return;

    // ---- prologue: load F for iteration 0 (clamped) ----
    float fr[9];
    {
        long long sE = s0 + l; if (sE > n - 1) sE = n - 1;
        const float* fp = Fs + sE * 9;
        #pragma unroll
        for (int q = 0; q < 9; ++q) fr[q] = fp[q];
    }

    for (int it = 0; it < iters; ++it) {
        long long ws = s0 + (long long)it * 64;
        if (ws >= n) break;

        // ---- prefetch next iteration's F early (hides HBM latency) ----
        float nf[9];
        const bool havenext = (it + 1 < iters) && (ws + 64 < n);
        if (havenext) {
            long long sE = ws + 64 + l; if (sE > n - 1) sE = n - 1;
            const float* fp = Fs + sE * 9;
            #pragma unroll
            for (int q = 0; q < 9; ++q) nf[q] = fp[q];
        }

        float a = fr[0], b = fr[1], cc = fr[2];
        float d = fr[3], e = fr[4], f5 = fr[5];
        float g7 = fr[6], h7 = fr[7], i8 = fr[8];

        // ---- features (f32 compute, f16 store): F(9), cofactor(9), det ----
        float C00 = e * i8 - f5 * h7;
        float C01 = f5 * g7 - d * i8;
        float C02 = d * h7 - e * g7;
        float det = fmaf(a, C00, fmaf(b, C01, cc * C02));
        float C10 = cc * h7 - b * i8;
        float C11 = a * i8 - cc * g7;
        float C12 = b * g7 - a * h7;
        float C20 = b * f5 - cc * e;
        float C21 = cc * d - a * f5;
        float C22 = a * e - b * d;

        // ---- write this sample's 19 features (+pad) to per-wave LDS ----
        {
            uint2 v;
            v.x = pk2(a,   b);   v.y = pk2(cc,  d);   basep[l*5 + 0] = v;
            v.x = pk2(e,   f5);  v.y = pk2(g7,  h7);  basep[l*5 + 1] = v;
            v.x = pk2(i8,  C00); v.y = pk2(C01, C02); basep[l*5 + 2] = v;
            v.x = pk2(C10, C11); v.y = pk2(C12, C20); basep[l*5 + 3] = v;
            v.x = pk2(C21, C22); v.y = pk2(det, 0.0f); basep[l*5 + 4] = v;
        }
        asm volatile("s_waitcnt lgkmcnt(0)" ::: "memory");

        // ---- gather B-frags: tile m covers samples 16m+c ----
        uint2 rlo0 = basep[(16*0 + c)*5 + g];
        uint2 rlo1 = basep[(16*1 + c)*5 + g];
        uint2 rlo2 = basep[(16*2 + c)*5 + g];
        uint2 rlo3 = basep[(16*3 + c)*5 + g];
        uint2 rhi0 = basep[(16*0 + c)*5 + 4];   // same addr across g: broadcast
        uint2 rhi1 = basep[(16*1 + c)*5 + 4];
        uint2 rhi2 = basep[(16*2 + c)*5 + 4];
        uint2 rhi3 = basep[(16*3 + c)*5 + 4];

        // ---- Layer 1: single K=32 MFMA per tile; output in t-domain ----
        f32x4 t10 = __builtin_amdgcn_mfma_f32_16x16x32_f16(a1, h8(rlo0, rhi0), cb1, 0, 0, 0);
        f32x4 t11 = __builtin_amdgcn_mfma_f32_16x16x32_f16(a1, h8(rlo1, rhi1), cb1, 0, 0, 0);
        f32x4 t12 = __builtin_amdgcn_mfma_f32_16x16x32_f16(a1, h8(rlo2, rhi2), cb1, 0, 0, 0);
        f32x4 t13 = __builtin_amdgcn_mfma_f32_16x16x32_f16(a1, h8(rlo3, rhi3), cb1, 0, 0, 0);

        // packed-f16 softplus: D-layout == next B-layout, output IS the frag
        uint2 u0, u1, u2, u3;
        u0.x = sp2_any(t10[0], t10[1]); u0.y = sp2_any(t10[2], t10[3]);
        u1.x = sp2_any(t11[0], t11[1]); u1.y = sp2_any(t11[2], t11[3]);
        u2.x = sp2_any(t12[0], t12[1]); u2.y = sp2_any(t12[2], t12[3]);
        u3.x = sp2_any(t13[0], t13[1]); u3.y = sp2_any(t13[2], t13[3]);

        // ---- Layer 2 ----
        f32x4 d20 = __builtin_amdgcn_mfma_f32_16x16x16f16(a2, h4(u0), cb2, 0, 0, 0);
        f32x4 d21 = __builtin_amdgcn_mfma_f32_16x16x16f16(a2, h4(u1), cb2, 0, 0, 0);
        f32x4 d22 = __builtin_amdgcn_mfma_f32_16x16x16f16(a2, h4(u2), cb2, 0, 0, 0);
        f32x4 d23 = __builtin_amdgcn_mfma_f32_16x16x16f16(a2, h4(u3), cb2, 0, 0, 0);

        u0.x = sp2_pos(d20[0], d20[1]); u0.y = sp2_pos(d20[2], d20[3]);
        u1.x = sp2_pos(d21[0], d21[1]); u1.y = sp2_pos(d21[2], d21[3]);
        u2.x = sp2_pos(d22[0], d22[1]); u2.y = sp2_pos(d22[2], d22[3]);
        u3.x = sp2_pos(d23[0], d23[1]); u3.y = sp2_pos(d23[2], d23[3]);

        // ---- Layer 3 ----
        f32x4 d30 = __builtin_amdgcn_mfma_f32_16x16x16f16(a3, h4(u0), cb3, 0, 0, 0);
        f32x4 d31 = __builtin_amdgcn_mfma_f32_16x16x16f16(a3, h4(u1), cb3, 0, 0, 0);
        f32x4 d32 = __builtin_amdgcn_mfma_f32_16x16x16f16(a3, h4(u2), cb3, 0, 0, 0);
        f32x4 d33 = __builtin_amdgcn_mfma_f32_16x16x16f16(a3, h4(u3), cb3, 0, 0, 0);

        u0.x = sp2_pos(d30[0], d30[1]); u0.y = sp2_pos(d30[2], d30[3]);
        u1.x = sp2_pos(d31[0], d31[1]); u1.y = sp2_pos(d31[2], d31[3]);
        u2.x = sp2_pos(d32[0], d32[1]); u2.y = sp2_pos(d32[2], d32[3]);
        u3.x = sp2_pos(d33[0], d33[1]); u3.y = sp2_pos(d33[2], d33[3]);

        // ---- Layer 4 via replicated-A MFMA: D[m][s] = y[s] for all m ----
        f32x4 d40 = __builtin_amdgcn_mfma_f32_16x16x16f16(a4, h4(u0), cb4, 0, 0, 0);
        f32x4 d41 = __builtin_amdgcn_mfma_f32_16x16x16f16(a4, h4(u1), cb4, 0, 0, 0);
        f32x4 d42 = __builtin_amdgcn_mfma_f32_16x16x16f16(a4, h4(u2), cb4, 0, 0, 0);
        f32x4 d43 = __builtin_amdgcn_mfma_f32_16x16x16f16(a4, h4(u3), cb4, 0, 0, 0);

        // lane (g,c) outputs sample l = 16g + c from tile g
        float yo = (g == 0) ? d40[0] : ((g == 1) ? d41[0] : ((g == 2) ? d42[0] : d43[0]));
        if (ws + l < n) out[ws + l] = yo;

        // rotate prefetched F into place
        if (havenext) {
            #pragma unroll
            for (int q = 0; q < 9; ++q) fr[q] = nf[q];
        }
    }
}

extern "C" void kernel_launch(void* const* d_in, const int* in_sizes, int n_in,
                              void* d_out, int out_size, void* d_ws, size_t ws_size,
                              hipStream_t stream) {
    const float* Fs = (const float*)d_in[0];
    const float* W1 = (const float*)d_in[1];
    const float* b1 = (const float*)d_in[2];
    const float* W2 = (const float*)d_in[3];
    const float* b2 = (const float*)d_in[4];
    const float* W3 = (const float*)d_in[5];
    const float* b3 = (const float*)d_in[6];
    const float* W4 = (const float*)d_in[7];
    const float* b4 = (const float*)d_in[8];
    float* out = (float*)d_out;

    int n = in_sizes[0] / 9;
    int waves = (n + 63) / 64;
    int iters = (waves + BLOCKS * 4 - 1) / (BLOCKS * 4);
    mlp_mfma_kernel<<<BLOCKS, TPB, 0, stream>>>(Fs, W1, b1, W2, b2, W3, b3, W4, b4,
                                                out, n, iters);
}

// Round 18
// 28.068 us; speedup vs baseline: 1.1043x; 1.0019x over previous
//
#include <hip/hip_runtime.h>
#include <hip/hip_fp16.h>
#include <math.h>

#define TPB 256
#define NODES 16
#define BLOCKS 2048

typedef float f32x4 __attribute__((ext_vector_type(4)));
typedef _Float16 half4 __attribute__((ext_vector_type(4)));
typedef _Float16 half8 __attribute__((ext_vector_type(8)));
typedef _Float16 h2 __attribute__((ext_vector_type(2)));

#define LOG2E 1.44269504088896340736f
#define LN2   0.69314718055994530942f

__device__ __forceinline__ _Float16 hx2(_Float16 x) {
    __half h = __builtin_bit_cast(__half, x);
    __half r = hexp2(h);
    return __builtin_bit_cast(_Float16, r);
}

// packed f16 softplus in log2 domain, 2 values per call, 3-FMA form.
// softplus(t*ln2)/ln2 = max(t,0) + log2(1+2^-|t|);  log2(1+e) ~= e*(c1+e*(c2+e*c3))
__device__ __forceinline__ unsigned int sp2_pos(float v0, float v1) {
    // t >= 0 guaranteed (W2,W3 >= 0 via jnp.abs, h >= 0, b = 0)
    h2 h = __builtin_bit_cast(h2, __builtin_amdgcn_cvt_pkrtz(v0, v1));
    h2 e = { hx2((_Float16)(-h[0])), hx2((_Float16)(-h[1])) };
    const h2 c3 = {(_Float16)0.154358f,  (_Float16)0.154358f};
    const h2 c2 = {(_Float16)-0.571177f, (_Float16)-0.571177f};
    const h2 c1 = {(_Float16)1.416467f,  (_Float16)1.416467f};
    h2 q = __builtin_elementwise_fma(e, __builtin_elementwise_fma(e, c3, c2), c1);
    h2 r = __builtin_elementwise_fma(e, q, h);
    return __builtin_bit_cast(unsigned int, r);
}
__device__ __forceinline__ unsigned int sp2_any(float v0, float v1) {
    h2 h = __builtin_bit_cast(h2, __builtin_amdgcn_cvt_pkrtz(v0, v1));
    const h2 z = {(_Float16)0.0f, (_Float16)0.0f};
    h2 m  = __builtin_elementwise_max(h, z);
    h2 nt = __builtin_elementwise_min(h, -h);   // -|t| (neg folds to modifier)
    h2 e = { hx2(nt[0]), hx2(nt[1]) };
    const h2 c3 = {(_Float16)0.154358f,  (_Float16)0.154358f};
    const h2 c2 = {(_Float16)-0.571177f, (_Float16)-0.571177f};
    const h2 c1 = {(_Float16)1.416467f,  (_Float16)1.416467f};
    h2 q = __builtin_elementwise_fma(e, __builtin_elementwise_fma(e, c3, c2), c1);
    h2 r = __builtin_elementwise_fma(e, q, m);
    return __builtin_bit_cast(unsigned int, r);
}
__device__ __forceinline__ unsigned int pk2(float a, float b) {
    return __builtin_bit_cast(unsigned int, __builtin_amdgcn_cvt_pkrtz(a, b));
}
__device__ __forceinline__ half4 h4(uint2 u) {
    return __builtin_bit_cast(half4, u);
}
__device__ __forceinline__ half8 h8(uint2 lo, uint2 hi) {
    uint4 u; u.x = lo.x; u.y = lo.y; u.z = hi.x; u.w = hi.y;
    return __builtin_bit_cast(half8, u);
}

__global__ __launch_bounds__(TPB, 4) void mlp_mfma_kernel(
    const float* __restrict__ Fs,
    const float* __restrict__ W1, const float* __restrict__ b1,
    const float* __restrict__ W2, const float* __restrict__ b2,
    const float* __restrict__ W3, const float* __restrict__ b3,
    const float* __restrict__ W4, const float* __restrict__ b4,
    float* __restrict__ out, int n, int iters)
{
    __shared__ uint2 lds[4][320];        // per-wave: 64 samples x 5 uint2 (19 f16 feats + pad)
    const int tid = threadIdx.x;
    const int l = tid & 63, w = tid >> 6;
    const int g = l >> 4, c = l & 15;

    // ---- one-time fragments/biases; no weight loads in the loop ----
    // L1: single K=32 MFMA. A8: j=0..3 -> k=4g+j; j=4..7 -> k=16+4g+(j-4)
    //     (W1 rows 19..31 are zero, so B hi garbage-but-finite is safe for g>0).
    // L4: replicated-A trick (all rows = W4*ln2), C = 0 -> D[m][s] = y[s]-b4.
    half8 a1;
    half4 a2, a3, a4;
    f32x4 cb1, cb2, cb3;
    #pragma unroll
    for (int j = 0; j < 4; ++j) {
        a1[j]   = (_Float16)(W1[(4*g+j)*NODES + c] * LOG2E);
        a1[4+j] = (_Float16)((g == 0 && j < 3) ? W1[(16+j)*NODES + c] * LOG2E : 0.0f);
        a2[j]   = (_Float16)W2[(4*g+j)*NODES + c];
        a3[j]   = (_Float16)W3[(4*g+j)*NODES + c];
        a4[j]   = (_Float16)(W4[4*g+j] * LN2);
    }
    const float b4s = b4[0];
    #pragma unroll
    for (int i = 0; i < 4; ++i) {
        cb1[i] = b1[4*g+i] * LOG2E;
        cb2[i] = b2[4*g+i] * LOG2E;
        cb3[i] = b3[4*g+i] * LOG2E;
    }
    const f32x4 zero4 = {0.0f, 0.0f, 0.0f, 0.0f};

    uint2* basep = &lds[w][0];
    const long long s0 = ((long long)blockIdx.x * 4 + w) * (64LL * iters);
    if (s0 >= n) return;

    // ---- prologue: load F for iteration 0 (clamped) ----
    float fr[9];
    {
        long long sE = s0 + l; if (sE > n - 1) sE = n - 1;
        const float* fp = Fs + sE * 9;
        #pragma unroll
        for (int q = 0; q < 9; ++q) fr[q] = fp[q];
    }

    for (int it = 0; it < iters; ++it) {
        long long ws = s0 + (long long)it * 64;
        if (ws >= n) break;

        float a = fr[0], b = fr[1], cc = fr[2];
        float d = fr[3], e = fr[4], f5 = fr[5];
        float g7 = fr[6], h7 = fr[7], i8 = fr[8];

        // fr is dead now -> prefetch next iteration's F directly into fr
        // (issues ~a full iteration ahead of its use; no double buffer needed)
        const bool havenext = (it + 1 < iters) && (ws + 64 < n);
        if (havenext) {
            long long sE = ws + 64 + l; if (sE > n - 1) sE = n - 1;
            const float* fp = Fs + sE * 9;
            #pragma unroll
            for (int q = 0; q < 9; ++q) fr[q] = fp[q];
        }

        // ---- features (f32 compute, f16 store): F(9), cofactor(9), det ----
        float C00 = e * i8 - f5 * h7;
        float C01 = f5 * g7 - d * i8;
        float C02 = d * h7 - e * g7;
        float det = fmaf(a, C00, fmaf(b, C01, cc * C02));
        float C10 = cc * h7 - b * i8;
        float C11 = a * i8 - cc * g7;
        float C12 = b * g7 - a * h7;
        float C20 = b * f5 - cc * e;
        float C21 = cc * d - a * f5;
        float C22 = a * e - b * d;

        // ---- write this sample's 19 features (+pad) to per-wave LDS ----
        {
            uint2 v;
            v.x = pk2(a,   b);   v.y = pk2(cc,  d);   basep[l*5 + 0] = v;
            v.x = pk2(e,   f5);  v.y = pk2(g7,  h7);  basep[l*5 + 1] = v;
            v.x = pk2(i8,  C00); v.y = pk2(C01, C02); basep[l*5 + 2] = v;
            v.x = pk2(C10, C11); v.y = pk2(C12, C20); basep[l*5 + 3] = v;
            v.x = pk2(C21, C22); v.y = pk2(det, 0.0f); basep[l*5 + 4] = v;
        }
        asm volatile("s_waitcnt lgkmcnt(0)" ::: "memory");

        // ---- gather B-frags: tile m covers samples 16m+c ----
        uint2 rlo0 = basep[(16*0 + c)*5 + g];
        uint2 rlo1 = basep[(16*1 + c)*5 + g];
        uint2 rlo2 = basep[(16*2 + c)*5 + g];
        uint2 rlo3 = basep[(16*3 + c)*5 + g];
        uint2 rhi0 = basep[(16*0 + c)*5 + 4];   // same addr across g: broadcast
        uint2 rhi1 = basep[(16*1 + c)*5 + 4];
        uint2 rhi2 = basep[(16*2 + c)*5 + 4];
        uint2 rhi3 = basep[(16*3 + c)*5 + 4];

        // ---- Layer 1: single K=32 MFMA per tile; output in t-domain ----
        f32x4 t10 = __builtin_amdgcn_mfma_f32_16x16x32_f16(a1, h8(rlo0, rhi0), cb1, 0, 0, 0);
        f32x4 t11 = __builtin_amdgcn_mfma_f32_16x16x32_f16(a1, h8(rlo1, rhi1), cb1, 0, 0, 0);
        f32x4 t12 = __builtin_amdgcn_mfma_f32_16x16x32_f16(a1, h8(rlo2, rhi2), cb1, 0, 0, 0);
        f32x4 t13 = __builtin_amdgcn_mfma_f32_16x16x32_f16(a1, h8(rlo3, rhi3), cb1, 0, 0, 0);

        // packed-f16 softplus: D-layout == next B-layout, output IS the frag
        uint2 u0, u1, u2, u3;
        u0.x = sp2_any(t10[0], t10[1]); u0.y = sp2_any(t10[2], t10[3]);
        u1.x = sp2_any(t11[0], t11[1]); u1.y = sp2_any(t11[2], t11[3]);
        u2.x = sp2_any(t12[0], t12[1]); u2.y = sp2_any(t12[2], t12[3]);
        u3.x = sp2_any(t13[0], t13[1]); u3.y = sp2_any(t13[2], t13[3]);

        // ---- Layer 2 ----
        f32x4 d20 = __builtin_amdgcn_mfma_f32_16x16x16f16(a2, h4(u0), cb2, 0, 0, 0);
        f32x4 d21 = __builtin_amdgcn_mfma_f32_16x16x16f16(a2, h4(u1), cb2, 0, 0, 0);
        f32x4 d22 = __builtin_amdgcn_mfma_f32_16x16x16f16(a2, h4(u2), cb2, 0, 0, 0);
        f32x4 d23 = __builtin_amdgcn_mfma_f32_16x16x16f16(a2, h4(u3), cb2, 0, 0, 0);

        u0.x = sp2_pos(d20[0], d20[1]); u0.y = sp2_pos(d20[2], d20[3]);
        u1.x = sp2_pos(d21[0], d21[1]); u1.y = sp2_pos(d21[2], d21[3]);
        u2.x = sp2_pos(d22[0], d22[1]); u2.y = sp2_pos(d22[2], d22[3]);
        u3.x = sp2_pos(d23[0], d23[1]); u3.y = sp2_pos(d23[2], d23[3]);

        // ---- Layer 3 ----
        f32x4 d30 = __builtin_amdgcn_mfma_f32_16x16x16f16(a3, h4(u0), cb3, 0, 0, 0);
        f32x4 d31 = __builtin_amdgcn_mfma_f32_16x16x16f16(a3, h4(u1), cb3, 0, 0, 0);
        f32x4 d32 = __builtin_amdgcn_mfma_f32_16x16x16f16(a3, h4(u2), cb3, 0, 0, 0);
        f32x4 d33 = __builtin_amdgcn_mfma_f32_16x16x16f16(a3, h4(u3), cb3, 0, 0, 0);

        u0.x = sp2_pos(d30[0], d30[1]); u0.y = sp2_pos(d30[2], d30[3]);
        u1.x = sp2_pos(d31[0], d31[1]); u1.y = sp2_pos(d31[2], d31[3]);
        u2.x = sp2_pos(d32[0], d32[1]); u2.y = sp2_pos(d32[2], d32[3]);
        u3.x = sp2_pos(d33[0], d33[1]); u3.y = sp2_pos(d33[2], d33[3]);

        // ---- Layer 4 via replicated-A MFMA, C = 0: D[m][s] = y[s] - b4 ----
        f32x4 d40 = __builtin_amdgcn_mfma_f32_16x16x16f16(a4, h4(u0), zero4, 0, 0, 0);
        f32x4 d41 = __builtin_amdgcn_mfma_f32_16x16x16f16(a4, h4(u1), zero4, 0, 0, 0);
        f32x4 d42 = __builtin_amdgcn_mfma_f32_16x16x16f16(a4, h4(u2), zero4, 0, 0, 0);
        f32x4 d43 = __builtin_amdgcn_mfma_f32_16x16x16f16(a4, h4(u3), zero4, 0, 0, 0);

        // lane (g,c) outputs sample l = 16g + c from tile g
        float yo = (g == 0) ? d40[0] : ((g == 1) ? d41[0] : ((g == 2) ? d42[0] : d43[0]));
        yo += b4s;
        if (ws + l < n) out[ws + l] = yo;
    }
}

extern "C" void kernel_launch(void* const* d_in, const int* in_sizes, int n_in,
                              void* d_out, int out_size, void* d_ws, size_t ws_size,
                              hipStream_t stream) {
    const float* Fs = (const float*)d_in[0];
    const float* W1 = (const float*)d_in[1];
    const float* b1 = (const float*)d_in[2];
    const float* W2 = (const float*)d_in[3];
    const float* b2 = (const float*)d_in[4];
    const float* W3 = (const float*)d_in[5];
    const float* b3 = (const float*)d_in[6];
    const float* W4 = (const float*)d_in[7];
    const float* b4 = (const float*)d_in[8];
    float* out = (float*)d_out;

    int n = in_sizes[0] / 9;
    int waves = (n + 63) / 64;
    int iters = (waves + BLOCKS * 4 - 1) / (BLOCKS * 4);
    mlp_mfma_kernel<<<BLOCKS, TPB, 0, stream>>>(Fs, W1, b1, W2, b2, W3, b3, W4, b4,
                                                out, n, iters);
}